// Round 3
// baseline (473.888 us; speedup 1.0000x reference)
//
#include <hip/hip_runtime.h>
#include <hip/hip_bf16.h>

typedef __attribute__((ext_vector_type(8))) short short8;
typedef __attribute__((ext_vector_type(4))) float floatx4;

__device__ __forceinline__ short f2bf(float f) {
    unsigned u = __float_as_uint(f);
    u = u + 0x7fffu + ((u >> 16) & 1u);
    return (short)(u >> 16);
}

static constexpr int B_ = 4, S_ = 2048, D_ = 1024, H_ = 16, DH_ = 64;

// ---------------------------------------------------------------------------
// x convert: f32 -> bf16, 8 elements/thread
// ---------------------------------------------------------------------------
__global__ __launch_bounds__(256) void convert_x(const float* __restrict__ in,
                                                 short* __restrict__ out, int n8) {
    int i = blockIdx.x * 256 + threadIdx.x;
    if (i >= n8) return;
    const float4* p = (const float4*)(in + (size_t)i * 8);
    float4 a = p[0], b = p[1];
    short8 v;
    v[0] = f2bf(a.x); v[1] = f2bf(a.y); v[2] = f2bf(a.z); v[3] = f2bf(a.w);
    v[4] = f2bf(b.x); v[5] = f2bf(b.y); v[6] = f2bf(b.z); v[7] = f2bf(b.w);
    *(short8*)(out + (size_t)i * 8) = v;
}

// ---------------------------------------------------------------------------
// Tiled 64x64 transpose + f32->bf16: in [batch][M][N] f32 -> out [batch][N][M] bf16
// grid (M/64, N/64, batch)
// ---------------------------------------------------------------------------
__global__ __launch_bounds__(256) void transpose_cvt(const float* __restrict__ in,
                                                     short* __restrict__ out,
                                                     int M, int N) {
    __shared__ alignas(16) float t[64 * 68];
    int m0 = blockIdx.x * 64, n0 = blockIdx.y * 64;
    const float* inb = in + (size_t)blockIdx.z * M * N;
    short* outb = out + (size_t)blockIdx.z * M * N;
    int tid = threadIdx.x;
#pragma unroll
    for (int i = 0; i < 4; ++i) {
        int c = tid + i * 256;                 // 1024 float4-chunks
        int row = c >> 4, c4 = (c & 15) * 4;
        float4 v = *(const float4*)(inb + (size_t)(m0 + row) * N + n0 + c4);
        *(float4*)(t + row * 68 + c4) = v;
    }
    __syncthreads();
#pragma unroll
    for (int i = 0; i < 2; ++i) {
        int c = tid + i * 256;                 // 512 short8-chunks
        int row = c >> 3, c8 = (c & 7) * 8;    // row = n-offset, c8 = m-chunk
        short8 v;
#pragma unroll
        for (int j = 0; j < 8; ++j) v[j] = f2bf(t[(c8 + j) * 68 + row]);
        *(short8*)(outb + (size_t)(n0 + row) * M + m0 + c8) = v;
    }
}

// ---------------------------------------------------------------------------
// QKV projection: grid (S/64, B*H, 3). A = xb[b] (S x D, bf16), B^T = W?T[h] (64 x D, bf16).
// z=0 -> Q [B,H,S,DH]; z=1 -> K [B,H,S,DH]; z=2 -> V^T [B,H,DH,S]
// ---------------------------------------------------------------------------
__global__ __launch_bounds__(256) void qkv_gemm(const short* __restrict__ xb,
                                                const short* __restrict__ WqT,
                                                const short* __restrict__ WkT,
                                                const short* __restrict__ WvT,
                                                short* __restrict__ Q,
                                                short* __restrict__ K,
                                                short* __restrict__ VT) {
    __shared__ alignas(16) short At[64 * 72];
    __shared__ alignas(16) short Bt[64 * 72];
    int s0 = blockIdx.x * 64;
    int bh = blockIdx.y;
    int z = blockIdx.z;
    int b = bh >> 4, h = bh & 15;
    const short* WT = (z == 0) ? WqT : (z == 1) ? WkT : WvT;
    WT += (size_t)h * 64 * D_;
    const short* A = xb + (size_t)b * S_ * D_;
    int tid = threadIdx.x;
    int w = tid >> 6, l = tid & 63;
    int quad = l >> 4, lm = l & 15;

    floatx4 acc[4];
#pragma unroll
    for (int ct = 0; ct < 4; ++ct) acc[ct] = (floatx4)0.0f;

    for (int k0 = 0; k0 < D_; k0 += 64) {
#pragma unroll
        for (int i = 0; i < 2; ++i) {
            int c = tid + i * 256;
            int row = c >> 3, c8 = (c & 7) * 8;
            *(short8*)(At + row * 72 + c8) = *(const short8*)(A + (size_t)(s0 + row) * D_ + k0 + c8);
            *(short8*)(Bt + row * 72 + c8) = *(const short8*)(WT + (size_t)row * D_ + k0 + c8);
        }
        __syncthreads();
        short8 a0 = *(const short8*)(At + (w * 16 + lm) * 72 + quad * 8);
        short8 a1 = *(const short8*)(At + (w * 16 + lm) * 72 + 32 + quad * 8);
#pragma unroll
        for (int ct = 0; ct < 4; ++ct) {
            short8 b0 = *(const short8*)(Bt + (ct * 16 + lm) * 72 + quad * 8);
            short8 b1 = *(const short8*)(Bt + (ct * 16 + lm) * 72 + 32 + quad * 8);
            acc[ct] = __builtin_amdgcn_mfma_f32_16x16x32_bf16(a0, b0, acc[ct], 0, 0, 0);
            acc[ct] = __builtin_amdgcn_mfma_f32_16x16x32_bf16(a1, b1, acc[ct], 0, 0, 0);
        }
        __syncthreads();
    }

    if (z < 2) {
        short* O = (z == 0 ? Q : K) + ((size_t)bh * S_ + s0) * DH_;
#pragma unroll
        for (int ct = 0; ct < 4; ++ct)
#pragma unroll
            for (int r = 0; r < 4; ++r) {
                int row = w * 16 + quad * 4 + r;
                O[(size_t)row * DH_ + ct * 16 + lm] = f2bf(acc[ct][r]);
            }
    } else {
        // transpose tile via LDS -> VT[bh*64 + e][S]
#pragma unroll
        for (int ct = 0; ct < 4; ++ct)
#pragma unroll
            for (int r = 0; r < 4; ++r)
                At[(ct * 16 + lm) * 72 + w * 16 + quad * 4 + r] = f2bf(acc[ct][r]);
        __syncthreads();
#pragma unroll
        for (int i = 0; i < 2; ++i) {
            int c = tid + i * 256;
            int row = c >> 3, c8 = (c & 7) * 8;
            short8 v = *(const short8*)(At + row * 72 + c8);
            *(short8*)(VT + ((size_t)bh * 64 + row) * S_ + s0 + c8) = v;
        }
    }
}

// ---------------------------------------------------------------------------
// Causal flash attention: grid (S/64, B*H). Q,K: [B,H,S,DH]; VT: [B,H,DH,S].
// Output written in concat layout CC[b][s][h*DH+e], bf16.
// ---------------------------------------------------------------------------
__global__ __launch_bounds__(256) void attn_kernel(const short* __restrict__ Q,
                                                   const short* __restrict__ Kb,
                                                   const short* __restrict__ VT,
                                                   short* __restrict__ CC) {
    __shared__ alignas(16) short Kt[64 * 72];
    __shared__ alignas(16) short Vt[64 * 72];
    __shared__ alignas(16) short Pt[64 * 72];
    int qt = blockIdx.x;
    int bh = blockIdx.y;
    int b = bh >> 4, h = bh & 15;
    int q0 = qt * 64;
    int tid = threadIdx.x;
    int w = tid >> 6, l = tid & 63;
    int quad = l >> 4, lm = l & 15;

    const short* Qrow = Q + ((size_t)bh * S_ + q0 + w * 16 + lm) * DH_;
    short8 qa0 = *(const short8*)(Qrow + quad * 8);
    short8 qa1 = *(const short8*)(Qrow + 32 + quad * 8);

    floatx4 acc_o[4];
#pragma unroll
    for (int ct = 0; ct < 4; ++ct) acc_o[ct] = (floatx4)0.0f;
    float m_run[4], l_run[4];
#pragma unroll
    for (int r = 0; r < 4; ++r) { m_run[r] = -INFINITY; l_run[r] = 0.0f; }

    for (int kt = 0; kt <= qt; ++kt) {
#pragma unroll
        for (int i = 0; i < 2; ++i) {
            int c = tid + i * 256;
            int row = c >> 3, c8 = (c & 7) * 8;
            *(short8*)(Kt + row * 72 + c8) =
                *(const short8*)(Kb + ((size_t)bh * S_ + kt * 64 + row) * DH_ + c8);
            *(short8*)(Vt + row * 72 + c8) =
                *(const short8*)(VT + ((size_t)bh * 64 + row) * S_ + kt * 64 + c8);
        }
        __syncthreads();

        floatx4 sc[4];
#pragma unroll
        for (int ct = 0; ct < 4; ++ct) {
            short8 k0 = *(const short8*)(Kt + (ct * 16 + lm) * 72 + quad * 8);
            short8 k1 = *(const short8*)(Kt + (ct * 16 + lm) * 72 + 32 + quad * 8);
            floatx4 t = (floatx4)0.0f;
            t = __builtin_amdgcn_mfma_f32_16x16x32_bf16(qa0, k0, t, 0, 0, 0);
            t = __builtin_amdgcn_mfma_f32_16x16x32_bf16(qa1, k1, t, 0, 0, 0);
            sc[ct] = t * 0.125f;  // 1/sqrt(64)
        }
        if (kt == qt) {
#pragma unroll
            for (int ct = 0; ct < 4; ++ct)
#pragma unroll
                for (int r = 0; r < 4; ++r) {
                    int t_off = ct * 16 + lm, qoff = w * 16 + quad * 4 + r;
                    if (t_off > qoff) sc[ct][r] = -INFINITY;
                }
        }
        float p[4][4], alpha[4];
#pragma unroll
        for (int r = 0; r < 4; ++r) {
            float mx = fmaxf(fmaxf(sc[0][r], sc[1][r]), fmaxf(sc[2][r], sc[3][r]));
#pragma unroll
            for (int off = 1; off < 16; off <<= 1) mx = fmaxf(mx, __shfl_xor(mx, off));
            float m_new = fmaxf(m_run[r], mx);
            alpha[r] = (m_run[r] == -INFINITY) ? 0.0f : __expf(m_run[r] - m_new);
            m_run[r] = m_new;
            float s_ = 0.0f;
#pragma unroll
            for (int ct = 0; ct < 4; ++ct) {
                p[ct][r] = __expf(sc[ct][r] - m_new);
                s_ += p[ct][r];
            }
#pragma unroll
            for (int off = 1; off < 16; off <<= 1) s_ += __shfl_xor(s_, off);
            l_run[r] = l_run[r] * alpha[r] + s_;
        }
#pragma unroll
        for (int ct = 0; ct < 4; ++ct)
#pragma unroll
            for (int r = 0; r < 4; ++r) {
                acc_o[ct][r] *= alpha[r];
                Pt[(w * 16 + quad * 4 + r) * 72 + ct * 16 + lm] = f2bf(p[ct][r]);
            }
        __syncthreads();
        short8 pa0 = *(const short8*)(Pt + (w * 16 + lm) * 72 + quad * 8);
        short8 pa1 = *(const short8*)(Pt + (w * 16 + lm) * 72 + 32 + quad * 8);
#pragma unroll
        for (int ct = 0; ct < 4; ++ct) {
            short8 v0 = *(const short8*)(Vt + (ct * 16 + lm) * 72 + quad * 8);
            short8 v1 = *(const short8*)(Vt + (ct * 16 + lm) * 72 + 32 + quad * 8);
            acc_o[ct] = __builtin_amdgcn_mfma_f32_16x16x32_bf16(pa0, v0, acc_o[ct], 0, 0, 0);
            acc_o[ct] = __builtin_amdgcn_mfma_f32_16x16x32_bf16(pa1, v1, acc_o[ct], 0, 0, 0);
        }
        __syncthreads();
    }

    short* OC = CC + ((size_t)b * S_ + q0) * D_ + h * DH_;
#pragma unroll
    for (int ct = 0; ct < 4; ++ct)
#pragma unroll
        for (int r = 0; r < 4; ++r) {
            int row = w * 16 + quad * 4 + r;
            float inv = 1.0f / l_run[r];
            OC[(size_t)row * D_ + ct * 16 + lm] = f2bf(acc_o[ct][r] * inv);
        }
}

// ---------------------------------------------------------------------------
// Output projection: out[M=B*S][D] = CC @ Wo + bo (FP32 out). grid (M/64, D/64).
// ---------------------------------------------------------------------------
__global__ __launch_bounds__(256) void out_proj(const short* __restrict__ CC,
                                                const short* __restrict__ WoT,
                                                const float* __restrict__ bo,
                                                float* __restrict__ out) {
    __shared__ alignas(16) short At[64 * 72];
    __shared__ alignas(16) short Bt[64 * 72];
    int m0 = blockIdx.x * 64, n0 = blockIdx.y * 64;
    int tid = threadIdx.x;
    int w = tid >> 6, l = tid & 63;
    int quad = l >> 4, lm = l & 15;

    floatx4 acc[4];
#pragma unroll
    for (int ct = 0; ct < 4; ++ct) acc[ct] = (floatx4)0.0f;

    for (int k0 = 0; k0 < D_; k0 += 64) {
#pragma unroll
        for (int i = 0; i < 2; ++i) {
            int c = tid + i * 256;
            int row = c >> 3, c8 = (c & 7) * 8;
            *(short8*)(At + row * 72 + c8) = *(const short8*)(CC + (size_t)(m0 + row) * D_ + k0 + c8);
            *(short8*)(Bt + row * 72 + c8) = *(const short8*)(WoT + (size_t)(n0 + row) * D_ + k0 + c8);
        }
        __syncthreads();
        short8 a0 = *(const short8*)(At + (w * 16 + lm) * 72 + quad * 8);
        short8 a1 = *(const short8*)(At + (w * 16 + lm) * 72 + 32 + quad * 8);
#pragma unroll
        for (int ct = 0; ct < 4; ++ct) {
            short8 b0 = *(const short8*)(Bt + (ct * 16 + lm) * 72 + quad * 8);
            short8 b1 = *(const short8*)(Bt + (ct * 16 + lm) * 72 + 32 + quad * 8);
            acc[ct] = __builtin_amdgcn_mfma_f32_16x16x32_bf16(a0, b0, acc[ct], 0, 0, 0);
            acc[ct] = __builtin_amdgcn_mfma_f32_16x16x32_bf16(a1, b1, acc[ct], 0, 0, 0);
        }
        __syncthreads();
    }
#pragma unroll
    for (int ct = 0; ct < 4; ++ct)
#pragma unroll
        for (int r = 0; r < 4; ++r) {
            int row = m0 + w * 16 + quad * 4 + r;
            int col = n0 + ct * 16 + lm;
            out[(size_t)row * D_ + col] = acc[ct][r] + bo[col];
        }
}

extern "C" void kernel_launch(void* const* d_in, const int* in_sizes, int n_in,
                              void* d_out, int out_size, void* d_ws, size_t ws_size,
                              hipStream_t stream) {
    const float* x  = (const float*)d_in[0];
    const float* Wq = (const float*)d_in[1];
    const float* Wk = (const float*)d_in[2];
    const float* Wv = (const float*)d_in[3];
    const float* Wo = (const float*)d_in[4];
    const float* bo = (const float*)d_in[5];
    float* out = (float*)d_out;
    short* ws = (short*)d_ws;

    const size_t WSZ = (size_t)H_ * D_ * DH_;        // 1,048,576
    const size_t QSZ = (size_t)B_ * H_ * S_ * DH_;   // 8,388,608
    short* WqT = ws;
    short* WkT = WqT + WSZ;
    short* WvT = WkT + WSZ;
    short* WoT = WvT + WSZ;
    short* xb  = WoT + (size_t)D_ * D_;
    short* Qb  = xb + (size_t)B_ * S_ * D_;
    short* Kb  = Qb + QSZ;
    short* VTb = Kb + QSZ;
    short* CCb = VTb + QSZ;

    convert_x<<<(B_ * S_ * D_ / 8 + 255) / 256, 256, 0, stream>>>(x, xb, B_ * S_ * D_ / 8);
    transpose_cvt<<<dim3(D_ / 64, DH_ / 64, H_), 256, 0, stream>>>(Wq, WqT, D_, DH_);
    transpose_cvt<<<dim3(D_ / 64, DH_ / 64, H_), 256, 0, stream>>>(Wk, WkT, D_, DH_);
    transpose_cvt<<<dim3(D_ / 64, DH_ / 64, H_), 256, 0, stream>>>(Wv, WvT, D_, DH_);
    transpose_cvt<<<dim3(D_ / 64, D_ / 64, 1), 256, 0, stream>>>(Wo, WoT, D_, D_);
    qkv_gemm<<<dim3(S_ / 64, B_ * H_, 3), 256, 0, stream>>>(xb, WqT, WkT, WvT, Qb, Kb, VTb);
    attn_kernel<<<dim3(S_ / 64, B_ * H_), 256, 0, stream>>>(Qb, Kb, VTb, CCb);
    out_proj<<<dim3((B_ * S_) / 64, D_ / 64), 256, 0, stream>>>(CCb, WoT, bo, out);
}

// Round 4
// 345.868 us; speedup vs baseline: 1.3701x; 1.3701x over previous
//
#include <hip/hip_runtime.h>
#include <hip/hip_bf16.h>

typedef __attribute__((ext_vector_type(8))) short short8;
typedef __attribute__((ext_vector_type(4))) float floatx4;

__device__ __forceinline__ short f2bf(float f) {
    unsigned u = __float_as_uint(f);
    u = u + 0x7fffu + ((u >> 16) & 1u);
    return (short)(u >> 16);
}
// truncating convert (values in [0,1], used for P only — saves VALU in the hot softmax)
__device__ __forceinline__ short f2bf_rz(float f) {
    return (short)(__float_as_uint(f) >> 16);
}

static constexpr int B_ = 4, S_ = 2048, D_ = 1024, H_ = 16, DH_ = 64;

// ---------------------------------------------------------------------------
// x convert: f32 -> bf16, 8 elements/thread
// ---------------------------------------------------------------------------
__global__ __launch_bounds__(256) void convert_x(const float* __restrict__ in,
                                                 short* __restrict__ out, int n8) {
    int i = blockIdx.x * 256 + threadIdx.x;
    if (i >= n8) return;
    const float4* p = (const float4*)(in + (size_t)i * 8);
    float4 a = p[0], b = p[1];
    short8 v;
    v[0] = f2bf(a.x); v[1] = f2bf(a.y); v[2] = f2bf(a.z); v[3] = f2bf(a.w);
    v[4] = f2bf(b.x); v[5] = f2bf(b.y); v[6] = f2bf(b.z); v[7] = f2bf(b.w);
    *(short8*)(out + (size_t)i * 8) = v;
}

// ---------------------------------------------------------------------------
// Tiled 64x64 transpose + f32->bf16: in [batch][M][N] f32 -> out [batch][N][M] bf16
// ---------------------------------------------------------------------------
__global__ __launch_bounds__(256) void transpose_cvt(const float* __restrict__ in,
                                                     short* __restrict__ out,
                                                     int M, int N) {
    __shared__ alignas(16) float t[64 * 68];
    int m0 = blockIdx.x * 64, n0 = blockIdx.y * 64;
    const float* inb = in + (size_t)blockIdx.z * M * N;
    short* outb = out + (size_t)blockIdx.z * M * N;
    int tid = threadIdx.x;
#pragma unroll
    for (int i = 0; i < 4; ++i) {
        int c = tid + i * 256;
        int row = c >> 4, c4 = (c & 15) * 4;
        float4 v = *(const float4*)(inb + (size_t)(m0 + row) * N + n0 + c4);
        *(float4*)(t + row * 68 + c4) = v;
    }
    __syncthreads();
#pragma unroll
    for (int i = 0; i < 2; ++i) {
        int c = tid + i * 256;
        int row = c >> 3, c8 = (c & 7) * 8;
        short8 v;
#pragma unroll
        for (int j = 0; j < 8; ++j) v[j] = f2bf(t[(c8 + j) * 68 + row]);
        *(short8*)(outb + (size_t)(n0 + row) * M + m0 + c8) = v;
    }
}

// ---------------------------------------------------------------------------
// m97-style 128x128 GEMM core: C = A[M][1024] * Bm[N][1024]^T, BK=64,
// global_load_lds width-16 staging, 4 waves in 2x2, 4x4 16x16x32 mfma per wave.
// ---------------------------------------------------------------------------
__device__ __forceinline__ void gemm128_core(const short* __restrict__ A,
                                             const short* __restrict__ Bm,
                                             short* ldsA, short* ldsB,
                                             int m0, int n0,
                                             floatx4 (&acc)[4][4],
                                             int w, int lane, int quad, int lm) {
    const int K = 1024;
    int wm = (w >> 1) * 64, wn = (w & 1) * 64;
    for (int k0 = 0; k0 < K; k0 += 64) {
#pragma unroll
        for (int i = 0; i < 4; ++i) {
            int r = w * 32 + i * 8;
            const short* ga = A + (size_t)(m0 + r + (lane >> 3)) * K + k0 + (lane & 7) * 8;
            __builtin_amdgcn_global_load_lds((const __attribute__((address_space(1))) void*)ga,
                                             (__attribute__((address_space(3))) void*)(ldsA + r * 64),
                                             16, 0, 0);
            const short* gb = Bm + (size_t)(n0 + r + (lane >> 3)) * K + k0 + (lane & 7) * 8;
            __builtin_amdgcn_global_load_lds((const __attribute__((address_space(1))) void*)gb,
                                             (__attribute__((address_space(3))) void*)(ldsB + r * 64),
                                             16, 0, 0);
        }
        __syncthreads();
#pragma unroll
        for (int ks = 0; ks < 2; ++ks) {
            short8 am[4], bn[4];
#pragma unroll
            for (int i = 0; i < 4; ++i)
                am[i] = *(const short8*)(ldsA + (wm + i * 16 + lm) * 64 + ks * 32 + quad * 8);
#pragma unroll
            for (int i = 0; i < 4; ++i)
                bn[i] = *(const short8*)(ldsB + (wn + i * 16 + lm) * 64 + ks * 32 + quad * 8);
#pragma unroll
            for (int mi = 0; mi < 4; ++mi)
#pragma unroll
                for (int ni = 0; ni < 4; ++ni)
                    acc[mi][ni] = __builtin_amdgcn_mfma_f32_16x16x32_bf16(am[mi], bn[ni], acc[mi][ni], 0, 0, 0);
        }
        __syncthreads();
    }
}

// ---------------------------------------------------------------------------
// QKV projection: grid (M/128=64, N/128=8, 3). A = xb [8192][1024].
// B = W?T [1024 n][1024 k] (heads contiguous along n).
// z=0 -> Q[b,h,s,e]; z=1 -> K[b,h,s,e]; z=2 -> VT[(b*1024+n)][s]
// ---------------------------------------------------------------------------
__global__ __launch_bounds__(256) void qkv_gemm128(const short* __restrict__ xb,
                                                   const short* __restrict__ WqT,
                                                   const short* __restrict__ WkT,
                                                   const short* __restrict__ WvT,
                                                   short* __restrict__ Q,
                                                   short* __restrict__ K,
                                                   short* __restrict__ VT) {
    __shared__ alignas(16) short ldsA[128 * 64];
    __shared__ alignas(16) short ldsB[128 * 64];
    int m0 = blockIdx.x * 128, n0 = blockIdx.y * 128, z = blockIdx.z;
    const short* Bm = (z == 0) ? WqT : (z == 1) ? WkT : WvT;
    int tid = threadIdx.x, w = tid >> 6, lane = tid & 63, quad = lane >> 4, lm = lane & 15;

    floatx4 acc[4][4];
#pragma unroll
    for (int mi = 0; mi < 4; ++mi)
#pragma unroll
        for (int ni = 0; ni < 4; ++ni) acc[mi][ni] = (floatx4)0.0f;

    gemm128_core(xb, Bm, ldsA, ldsB, m0, n0, acc, w, lane, quad, lm);

    int wm = (w >> 1) * 64, wn = (w & 1) * 64;
    int b = m0 >> 11;
    int sbase = m0 & 2047;

    if (z < 2) {
        short* O = (z == 0) ? Q : K;
#pragma unroll
        for (int mi = 0; mi < 4; ++mi)
#pragma unroll
            for (int ni = 0; ni < 4; ++ni) {
                int n = n0 + wn + ni * 16 + lm;
                int h = n >> 6, e = n & 63;
                size_t base = ((size_t)(b * 16 + h) * 2048) * 64 + (size_t)e;
#pragma unroll
                for (int r = 0; r < 4; ++r) {
                    int s = sbase + wm + mi * 16 + quad * 4 + r;
                    O[base + (size_t)s * 64] = f2bf(acc[mi][ni][r]);
                }
            }
    } else {
        // transpose 128x128 tile through LDS (two 64-n halves), write VT[b*1024+n][s]
        __syncthreads();
        short* t = ldsA;  // 64*136 = 8704 shorts per half, fits in 8192... (uses both arrays' 16384)
#pragma unroll
        for (int ph = 0; ph < 2; ++ph) {
            if ((w & 1) == ph) {
#pragma unroll
                for (int mi = 0; mi < 4; ++mi)
#pragma unroll
                    for (int ni = 0; ni < 4; ++ni) {
                        int nl = ni * 16 + lm;
#pragma unroll
                        for (int r = 0; r < 4; ++r) {
                            int ml = wm + mi * 16 + quad * 4 + r;
                            t[nl * 136 + ml] = f2bf(acc[mi][ni][r]);
                        }
                    }
            }
            __syncthreads();
#pragma unroll
            for (int i = 0; i < 4; ++i) {
                int c = tid + i * 256;
                int rowl = c >> 4, colc = (c & 15) * 8;
                short8 v = *(const short8*)(t + rowl * 136 + colc);
                size_t n = n0 + ph * 64 + rowl;
                *(short8*)(VT + ((size_t)b * 1024 + n) * 2048 + sbase + colc) = v;
            }
            __syncthreads();
        }
    }
}

// ---------------------------------------------------------------------------
// Output projection: out[8192][1024] f32 = CC @ WoT^T + bo. grid (64, 8).
// ---------------------------------------------------------------------------
__global__ __launch_bounds__(256) void outproj128(const short* __restrict__ CC,
                                                  const short* __restrict__ WoT,
                                                  const float* __restrict__ bo,
                                                  float* __restrict__ out) {
    __shared__ alignas(16) short ldsA[128 * 64];
    __shared__ alignas(16) short ldsB[128 * 64];
    int m0 = blockIdx.x * 128, n0 = blockIdx.y * 128;
    int tid = threadIdx.x, w = tid >> 6, lane = tid & 63, quad = lane >> 4, lm = lane & 15;

    floatx4 acc[4][4];
#pragma unroll
    for (int mi = 0; mi < 4; ++mi)
#pragma unroll
        for (int ni = 0; ni < 4; ++ni) acc[mi][ni] = (floatx4)0.0f;

    gemm128_core(CC, WoT, ldsA, ldsB, m0, n0, acc, w, lane, quad, lm);

    int wm = (w >> 1) * 64, wn = (w & 1) * 64;
#pragma unroll
    for (int mi = 0; mi < 4; ++mi)
#pragma unroll
        for (int ni = 0; ni < 4; ++ni) {
            int n = n0 + wn + ni * 16 + lm;
            float bb = bo[n];
#pragma unroll
            for (int r = 0; r < 4; ++r) {
                int m = m0 + wm + mi * 16 + quad * 4 + r;
                out[(size_t)m * 1024 + n] = acc[mi][ni][r] + bb;
            }
        }
}

// ---------------------------------------------------------------------------
// Causal flash attention: grid (16, B*H). Block handles q-tiles {pi, 31-pi}
// (uniform 33 k-tiles of work). Q,K: [B,H,S,DH]; VT: [B,H,DH,S].
// Pt rows are wave-private -> no barrier between Pt write and read.
// ---------------------------------------------------------------------------
__global__ __launch_bounds__(256) void attn_kernel(const short* __restrict__ Q,
                                                   const short* __restrict__ Kb,
                                                   const short* __restrict__ VT,
                                                   short* __restrict__ CC) {
    __shared__ alignas(16) short Kt[64 * 72];
    __shared__ alignas(16) short Vt[64 * 72];
    __shared__ alignas(16) short Pt[64 * 72];
    int pi = blockIdx.x;
    int bh = blockIdx.y;
    int b = bh >> 4, h = bh & 15;
    int tid = threadIdx.x;
    int w = tid >> 6, l = tid & 63;
    int quad = l >> 4, lm = l & 15;

    const short* Qbh = Q + (size_t)bh * S_ * DH_;
    const short* Kbh = Kb + (size_t)bh * S_ * DH_;
    const short* Vbh = VT + (size_t)bh * 64 * S_;

    for (int ps = 0; ps < 2; ++ps) {
        int qt = ps ? (31 - pi) : pi;
        int q0 = qt * 64;

        const short* Qrow = Qbh + (size_t)(q0 + w * 16 + lm) * DH_;
        short8 qa0 = *(const short8*)(Qrow + quad * 8);
        short8 qa1 = *(const short8*)(Qrow + 32 + quad * 8);

        floatx4 acc_o[4];
#pragma unroll
        for (int ct = 0; ct < 4; ++ct) acc_o[ct] = (floatx4)0.0f;
        float m_run[4], l_run[4];
#pragma unroll
        for (int r = 0; r < 4; ++r) { m_run[r] = -INFINITY; l_run[r] = 0.0f; }

        for (int kt = 0; kt <= qt; ++kt) {
#pragma unroll
            for (int i = 0; i < 2; ++i) {
                int c = tid + i * 256;
                int row = c >> 3, c8 = (c & 7) * 8;
                *(short8*)(Kt + row * 72 + c8) =
                    *(const short8*)(Kbh + (size_t)(kt * 64 + row) * DH_ + c8);
                *(short8*)(Vt + row * 72 + c8) =
                    *(const short8*)(Vbh + (size_t)row * S_ + kt * 64 + c8);
            }
            __syncthreads();

            floatx4 sc[4];
#pragma unroll
            for (int ct = 0; ct < 4; ++ct) {
                short8 k0 = *(const short8*)(Kt + (ct * 16 + lm) * 72 + quad * 8);
                short8 k1 = *(const short8*)(Kt + (ct * 16 + lm) * 72 + 32 + quad * 8);
                floatx4 t = (floatx4)0.0f;
                t = __builtin_amdgcn_mfma_f32_16x16x32_bf16(qa0, k0, t, 0, 0, 0);
                t = __builtin_amdgcn_mfma_f32_16x16x32_bf16(qa1, k1, t, 0, 0, 0);
                sc[ct] = t * 0.125f;  // 1/sqrt(64)
            }
            if (kt == qt) {
#pragma unroll
                for (int ct = 0; ct < 4; ++ct)
#pragma unroll
                    for (int r = 0; r < 4; ++r) {
                        int t_off = ct * 16 + lm, qoff = w * 16 + quad * 4 + r;
                        if (t_off > qoff) sc[ct][r] = -INFINITY;
                    }
            }
            float p[4][4], alpha[4];
#pragma unroll
            for (int r = 0; r < 4; ++r) {
                float mx = fmaxf(fmaxf(sc[0][r], sc[1][r]), fmaxf(sc[2][r], sc[3][r]));
#pragma unroll
                for (int off = 1; off < 16; off <<= 1) mx = fmaxf(mx, __shfl_xor(mx, off));
                float m_new = fmaxf(m_run[r], mx);
                alpha[r] = (m_run[r] == -INFINITY) ? 0.0f : __expf(m_run[r] - m_new);
                m_run[r] = m_new;
                float s_ = 0.0f;
#pragma unroll
                for (int ct = 0; ct < 4; ++ct) {
                    p[ct][r] = __expf(sc[ct][r] - m_new);
                    s_ += p[ct][r];
                }
#pragma unroll
                for (int off = 1; off < 16; off <<= 1) s_ += __shfl_xor(s_, off);
                l_run[r] = l_run[r] * alpha[r] + s_;
            }
            // Pt rows [16w,16w+16) are written and read only by wave w -> no barrier
#pragma unroll
            for (int ct = 0; ct < 4; ++ct)
#pragma unroll
                for (int r = 0; r < 4; ++r) {
                    acc_o[ct][r] *= alpha[r];
                    Pt[(w * 16 + quad * 4 + r) * 72 + ct * 16 + lm] = f2bf_rz(p[ct][r]);
                }
            short8 pa0 = *(const short8*)(Pt + (w * 16 + lm) * 72 + quad * 8);
            short8 pa1 = *(const short8*)(Pt + (w * 16 + lm) * 72 + 32 + quad * 8);
#pragma unroll
            for (int ct = 0; ct < 4; ++ct) {
                short8 v0 = *(const short8*)(Vt + (ct * 16 + lm) * 72 + quad * 8);
                short8 v1 = *(const short8*)(Vt + (ct * 16 + lm) * 72 + 32 + quad * 8);
                acc_o[ct] = __builtin_amdgcn_mfma_f32_16x16x32_bf16(pa0, v0, acc_o[ct], 0, 0, 0);
                acc_o[ct] = __builtin_amdgcn_mfma_f32_16x16x32_bf16(pa1, v1, acc_o[ct], 0, 0, 0);
            }
            __syncthreads();  // protects Kt/Vt restage next iteration / next ps
        }

        short* OC = CC + ((size_t)b * S_ + q0) * D_ + h * DH_;
#pragma unroll
        for (int ct = 0; ct < 4; ++ct)
#pragma unroll
            for (int r = 0; r < 4; ++r) {
                int row = w * 16 + quad * 4 + r;
                float inv = 1.0f / l_run[r];
                OC[(size_t)row * D_ + ct * 16 + lm] = f2bf(acc_o[ct][r] * inv);
            }
    }
}

extern "C" void kernel_launch(void* const* d_in, const int* in_sizes, int n_in,
                              void* d_out, int out_size, void* d_ws, size_t ws_size,
                              hipStream_t stream) {
    const float* x  = (const float*)d_in[0];
    const float* Wq = (const float*)d_in[1];
    const float* Wk = (const float*)d_in[2];
    const float* Wv = (const float*)d_in[3];
    const float* Wo = (const float*)d_in[4];
    const float* bo = (const float*)d_in[5];
    float* out = (float*)d_out;
    short* ws = (short*)d_ws;

    const size_t WSZ = (size_t)H_ * D_ * DH_;        // 1,048,576
    const size_t QSZ = (size_t)B_ * H_ * S_ * DH_;   // 8,388,608
    short* WqT = ws;
    short* WkT = WqT + WSZ;
    short* WvT = WkT + WSZ;
    short* WoT = WvT + WSZ;
    short* xb  = WoT + (size_t)D_ * D_;
    short* Qb  = xb + (size_t)B_ * S_ * D_;
    short* Kb  = Qb + QSZ;
    short* VTb = Kb + QSZ;
    short* CCb = VTb + QSZ;

    convert_x<<<(B_ * S_ * D_ / 8 + 255) / 256, 256, 0, stream>>>(x, xb, B_ * S_ * D_ / 8);
    transpose_cvt<<<dim3(D_ / 64, DH_ / 64, H_), 256, 0, stream>>>(Wq, WqT, D_, DH_);
    transpose_cvt<<<dim3(D_ / 64, DH_ / 64, H_), 256, 0, stream>>>(Wk, WkT, D_, DH_);
    transpose_cvt<<<dim3(D_ / 64, DH_ / 64, H_), 256, 0, stream>>>(Wv, WvT, D_, DH_);
    transpose_cvt<<<dim3(D_ / 64, D_ / 64, 1), 256, 0, stream>>>(Wo, WoT, D_, D_);
    qkv_gemm128<<<dim3(64, 8, 3), 256, 0, stream>>>(xb, WqT, WkT, WvT, Qb, Kb, VTb);
    attn_kernel<<<dim3(16, B_ * H_), 256, 0, stream>>>(Qb, Kb, VTb, CCb);
    outproj128<<<dim3(64, 8), 256, 0, stream>>>(CCb, WoT, bo, out);
}